// Round 9
// baseline (96.013 us; speedup 1.0000x reference)
//
#include <hip/hip_runtime.h>

typedef __attribute__((ext_vector_type(8))) short bf8;
typedef __attribute__((ext_vector_type(4))) float f4;

// ws layout (short-element offsets)
#define QBF  0         // q  bf16 [2048][256]
#define KBF  524288    // k  bf16 [2048][256]
#define REBF 1048576   // rel_emb bf16 [112][256], rows 99..111 zero

static __device__ __forceinline__ short bfr(float x) {
    union { float f; unsigned u; } v; v.f = x;
    return (short)((v.u + 0x7FFF + ((v.u >> 16) & 1)) >> 16);  // RNE
}
static __device__ __forceinline__ bf8 pack8(float4 a, float4 b) {
    bf8 r;
    r[0] = bfr(a.x); r[1] = bfr(a.y); r[2] = bfr(a.z); r[3] = bfr(a.w);
    r[4] = bfr(b.x); r[5] = bfr(b.y); r[6] = bfr(b.z); r[7] = bfr(b.w);
    return r;
}

// K1: blocks 0..255: proj GEMM tiles (M=64 x N=64). 512 thr = 8 waves; waves
// 0..3 compute n-cols 0..31 (nt 0,1), waves 4..7 n-cols 32..63 (nt 2,3) of the
// same M64 tile -> 2 waves/SIMD on all CUs, no duplicated work.
// Blocks 256..259: rel_emb fp32->bf16 cast.
__global__ __launch_bounds__(512) void proj_kernel(const float* __restrict__ queries,
                                                   const float* __restrict__ keys,
                                                   const float* __restrict__ bq,
                                                   const float* __restrict__ bk,
                                                   const float* __restrict__ Wq,
                                                   const float* __restrict__ Wk,
                                                   const float* __restrict__ rel_emb,
                                                   short* __restrict__ ws) {
    __shared__ short w_l[64 * 264];  // bf16 W tile, row stride 264 shorts
    int blk = blockIdx.x;
    int tid = threadIdx.x;

    if (blk >= 256) {
        // rel_emb cast: 4 blocks x 512 thr x 16 shorts, guard at 112*256=28672
        int idx = ((blk - 256) * 512 + tid) * 16;
        if (idx < 28672) {
            float4 a = make_float4(0.f, 0.f, 0.f, 0.f), b = a, c = a, d = a;
            if ((idx >> 8) < 99) {
                const float4* s = (const float4*)(rel_emb + idx);
                a = s[0]; b = s[1]; c = s[2]; d = s[3];
            }
            *(bf8*)(ws + REBF + idx) = pack8(a, b);
            *(bf8*)(ws + REBF + idx + 8) = pack8(c, d);
        }
        return;
    }

    int mat = blk >> 7;          // 0 = q, 1 = k
    int t = blk & 127;           // 32 m-tiles x 4 n-tiles
    int m0 = (t >> 2) * 64;
    int n0 = (t & 3) * 64;
    const float* x = mat ? keys : queries;
    const float* W = mat ? Wk : Wq;
    const float* bias = mat ? bk : bq;
    short* outp = ws + (mat ? KBF : QBF);

    int w = tid >> 6;            // 0..7
    int wm = w & 3;              // m-subtile 0..3
    int nh = w >> 2;             // n-half 0/1
    int lane = tid & 63;
    int n15 = lane & 15, quad = lane >> 4;

    // stage W[n0..n0+64)[0..256) fp32 -> bf16 LDS: 2048 chunks / 512 thr = 4 it
#pragma unroll
    for (int cc = 0; cc < 4; cc++) {
        int chunk = cc * 512 + tid;
        int row = chunk >> 5, col8 = chunk & 31;
        const float4* s = (const float4*)(W + (n0 + row) * 256 + col8 * 8);
        *(bf8*)&w_l[row * 264 + col8 * 8] = pack8(s[0], s[1]);
    }

    // A-frags: x rows m0 + wm*16 + n15, packed fp32->bf16
    int mrow = m0 + wm * 16 + n15;
    bf8 afr[8];
#pragma unroll
    for (int kk = 0; kk < 8; kk++) {
        const float4* ap = (const float4*)(x + mrow * 256 + kk * 32 + quad * 8);
        afr[kk] = pack8(ap[0], ap[1]);
    }
    __syncthreads();

    f4 z = {0.f, 0.f, 0.f, 0.f};
    f4 c[2] = {z, z};
#pragma unroll
    for (int nt = 0; nt < 2; nt++) {
        const short* wr = &w_l[((nh * 2 + nt) * 16 + n15) * 264 + quad * 8];
#pragma unroll
        for (int kk = 0; kk < 8; kk++) {
            bf8 bfrag = *(const bf8*)(wr + kk * 32);
            c[nt] = __builtin_amdgcn_mfma_f32_16x16x32_bf16(afr[kk], bfrag, c[nt], 0, 0, 0);
        }
    }

    int mbase = m0 + wm * 16 + quad * 4;
#pragma unroll
    for (int nt = 0; nt < 2; nt++) {
        int col = n0 + (nh * 2 + nt) * 16 + n15;
        float bv = bias[col];
#pragma unroll
        for (int reg = 0; reg < 4; reg++)
            outp[(mbase + reg) * 256 + col] = bfr(c[nt][reg] + bv);
    }
}

// K2: fused qk + qr + softmax. Block = (b, 8-row i-tile): grid 256 x 512 thr.
// A-rows duplicated (row = n15&7): 16x16 MFMA tile carries 8 real rows; dup
// lanes hit identical cache lines. Single-barrier online softmax: each wave
// stores (m_w, sum_w exp(x-m_w)); recombine M,S per-thread after one barrier.
__global__ __launch_bounds__(512) void attn_kernel(const int* __restrict__ relations,
                                                   const short* __restrict__ ws,
                                                   float* __restrict__ out) {
    __shared__ float qr_l[16][112];
    __shared__ float2 red[16][8];   // {wave max, wave expsum}

    int blk = blockIdx.x;
    int b = blk >> 6;
    int i0 = (blk & 63) * 8;
    int gi0 = b * 512 + i0;
    int w = threadIdx.x >> 6;
    int lane = threadIdx.x & 63;
    int n15 = lane & 15, quad = lane >> 4;
    int j0 = w * 64;

    // prefetch relations: C row m=quad*4+reg -> real row (quad&1)*4+reg
    const int* rb = relations + (gi0 + (quad & 1) * 4) * 512 + j0 + n15;
    int rv[4][4];
#pragma unroll
    for (int reg = 0; reg < 4; reg++)
#pragma unroll
        for (int nt = 0; nt < 4; nt++)
            rv[nt][reg] = rb[reg * 512 + nt * 16];

    const short* qbf = ws + QBF;
    const short* kbf = ws + KBF;
    const short* rebf = ws + REBF;

    // A-frags: q row gi0 + (n15&7)  (rows 8..15 duplicate 0..7)
    int arow = gi0 + (n15 & 7);
    bf8 afr[8];
#pragma unroll
    for (int kk = 0; kk < 8; kk++)
        afr[kk] = *(const bf8*)(qbf + arow * 256 + kk * 32 + quad * 8);

    f4 z = {0.f, 0.f, 0.f, 0.f};
    f4 c[4] = {z, z, z, z};
#pragma unroll
    for (int nt = 0; nt < 4; nt++) {
        int krow = b * 512 + j0 + nt * 16 + n15;
        const short* kr = kbf + krow * 256 + quad * 8;
#pragma unroll
        for (int kk = 0; kk < 8; kk++) {
            bf8 bfrag = *(const bf8*)(kr + kk * 32);
            c[nt] = __builtin_amdgcn_mfma_f32_16x16x32_bf16(afr[kk], bfrag, c[nt], 0, 0, 0);
        }
    }

    if (w < 7) {  // qr tile: rel rows w*16..w*16+15 (rebf zero-padded to 112)
        f4 cq = z;
        const short* rr = rebf + (w * 16 + n15) * 256 + quad * 8;
#pragma unroll
        for (int kk = 0; kk < 8; kk++) {
            bf8 bfrag = *(const bf8*)(rr + kk * 32);
            cq = __builtin_amdgcn_mfma_f32_16x16x32_bf16(afr[kk], bfrag, cq, 0, 0, 0);
        }
#pragma unroll
        for (int reg = 0; reg < 4; reg++)
            qr_l[quad * 4 + reg][w * 16 + n15] = cq[reg];  // dup rows get dup values
    }
    __syncthreads();

    const float scale = 0.0625f;  // 1/sqrt(256)
    float lg[4][4];
#pragma unroll
    for (int nt = 0; nt < 4; nt++)
#pragma unroll
        for (int reg = 0; reg < 4; reg++)
            lg[nt][reg] = (c[nt][reg] + qr_l[quad * 4 + reg][rv[nt][reg]]) * scale;

    // wave-local (m, expsum) per row; shfl over the 16 n15 lanes only (d<=8)
    float pm[4], psum[4];
#pragma unroll
    for (int reg = 0; reg < 4; reg++) {
        float m = fmaxf(fmaxf(lg[0][reg], lg[1][reg]), fmaxf(lg[2][reg], lg[3][reg]));
#pragma unroll
        for (int d = 1; d <= 8; d <<= 1) m = fmaxf(m, __shfl_xor(m, d, 64));
        pm[reg] = m;
        float s = 0.f;
#pragma unroll
        for (int nt = 0; nt < 4; nt++) {
            float e = __expf(lg[nt][reg] - m);
            lg[nt][reg] = e;
            s += e;
        }
#pragma unroll
        for (int d = 1; d <= 8; d <<= 1) s += __shfl_xor(s, d, 64);
        psum[reg] = s;
    }
    if (n15 == 0)
#pragma unroll
        for (int reg = 0; reg < 4; reg++) {
            red[quad * 4 + reg][w].x = pm[reg];
            red[quad * 4 + reg][w].y = psum[reg];
        }
    __syncthreads();

    // recombine: M = max_w m_w ; S = sum_w s_w * exp(m_w - M); f = exp(pm-M)/S
    float f[4];
#pragma unroll
    for (int reg = 0; reg < 4; reg++) {
        int row = quad * 4 + reg;
        float2 p0 = red[row][0], p1 = red[row][1], p2 = red[row][2], p3 = red[row][3];
        float2 p4 = red[row][4], p5 = red[row][5], p6 = red[row][6], p7 = red[row][7];
        float M = fmaxf(fmaxf(fmaxf(p0.x, p1.x), fmaxf(p2.x, p3.x)),
                        fmaxf(fmaxf(p4.x, p5.x), fmaxf(p6.x, p7.x)));
        float S = p0.y * __expf(p0.x - M) + p1.y * __expf(p1.x - M) +
                  p2.y * __expf(p2.x - M) + p3.y * __expf(p3.x - M) +
                  p4.y * __expf(p4.x - M) + p5.y * __expf(p5.x - M) +
                  p6.y * __expf(p6.x - M) + p7.y * __expf(p7.x - M);
        f[reg] = __expf(pm[reg] - M) / S;
    }

    if (quad < 2) {  // rows 0..7 real; quads 2,3 are duplicates
        float* ob = out + (gi0 + quad * 4) * 512 + j0 + n15;
#pragma unroll
        for (int reg = 0; reg < 4; reg++)
#pragma unroll
            for (int nt = 0; nt < 4; nt++)
                ob[reg * 512 + nt * 16] = lg[nt][reg] * f[reg];
    }
}

extern "C" void kernel_launch(void* const* d_in, const int* in_sizes, int n_in,
                              void* d_out, int out_size, void* d_ws, size_t ws_size,
                              hipStream_t stream) {
    const float* queries = (const float*)d_in[0];
    const float* keys = (const float*)d_in[1];
    const int* relations = (const int*)d_in[2];
    const float* Wq = (const float*)d_in[3];
    const float* bq = (const float*)d_in[4];
    const float* Wk = (const float*)d_in[5];
    const float* bk = (const float*)d_in[6];
    const float* rel_emb = (const float*)d_in[7];
    short* wss = (short*)d_ws;
    float* out = (float*)d_out;

    hipLaunchKernelGGL(proj_kernel, dim3(260), dim3(512), 0, stream,
                       queries, keys, bq, bk, Wq, Wk, rel_emb, wss);
    hipLaunchKernelGGL(attn_kernel, dim3(256), dim3(512), 0, stream, relations, wss, out);
}

// Round 10
// 94.413 us; speedup vs baseline: 1.0169x; 1.0169x over previous
//
#include <hip/hip_runtime.h>

typedef __attribute__((ext_vector_type(8))) short bf8;
typedef __attribute__((ext_vector_type(4))) float f4;

// ws layout (short-element offsets)
#define QBF  0         // q  bf16 [2048][256]
#define KBF  524288    // k  bf16 [2048][256]
#define REBF 1048576   // rel_emb bf16 [112][256], rows 99..111 zero

static __device__ __forceinline__ short bfr(float x) {
    union { float f; unsigned u; } v; v.f = x;
    return (short)((v.u + 0x7FFF + ((v.u >> 16) & 1)) >> 16);  // RNE
}
static __device__ __forceinline__ bf8 pack8(float4 a, float4 b) {
    bf8 r;
    r[0] = bfr(a.x); r[1] = bfr(a.y); r[2] = bfr(a.z); r[3] = bfr(a.w);
    r[4] = bfr(b.x); r[5] = bfr(b.y); r[6] = bfr(b.z); r[7] = bfr(b.w);
    return r;
}

// K1 (R8 shape — measured best): blocks 0..255: proj GEMM tiles (M=64 x N=64,
// 4 waves, 4 nt-tiles/wave); blocks 256..262: rel_emb fp32->bf16 cast.
// out[row][col] = sum_h x[row][h]*W[col][h] + bias[col].
__global__ __launch_bounds__(256) void proj_kernel(const float* __restrict__ queries,
                                                   const float* __restrict__ keys,
                                                   const float* __restrict__ bq,
                                                   const float* __restrict__ bk,
                                                   const float* __restrict__ Wq,
                                                   const float* __restrict__ Wk,
                                                   const float* __restrict__ rel_emb,
                                                   short* __restrict__ ws) {
    __shared__ short w_l[64 * 264];  // bf16 W tile, row stride 264 shorts
    int blk = blockIdx.x;
    int tid = threadIdx.x;

    if (blk >= 256) {
        // rel_emb cast: 7 blocks x 256 thr x 16 shorts = 28672 = 112*256
        int idx = ((blk - 256) * 256 + tid) * 16;
        float4 a = make_float4(0.f, 0.f, 0.f, 0.f), b = a, c = a, d = a;
        if ((idx >> 8) < 99) {
            const float4* s = (const float4*)(rel_emb + idx);
            a = s[0]; b = s[1]; c = s[2]; d = s[3];
        }
        *(bf8*)(ws + REBF + idx) = pack8(a, b);
        *(bf8*)(ws + REBF + idx + 8) = pack8(c, d);
        return;
    }

    int mat = blk >> 7;          // 0 = q, 1 = k
    int t = blk & 127;           // 32 m-tiles x 4 n-tiles
    int m0 = (t >> 2) * 64;
    int n0 = (t & 3) * 64;
    const float* x = mat ? keys : queries;
    const float* W = mat ? Wk : Wq;
    const float* bias = mat ? bk : bq;
    short* outp = ws + (mat ? KBF : QBF);

    int w = tid >> 6;
    int lane = tid & 63;
    int n15 = lane & 15, quad = lane >> 4;

    // stage W[n0..n0+64)[0..256) fp32 -> bf16 LDS (coalesced 32B/lane reads)
#pragma unroll
    for (int cc = 0; cc < 8; cc++) {
        int chunk = cc * 256 + tid;          // 2048 chunks of 8 floats
        int row = chunk >> 5, col8 = chunk & 31;
        const float4* s = (const float4*)(W + (n0 + row) * 256 + col8 * 8);
        *(bf8*)&w_l[row * 264 + col8 * 8] = pack8(s[0], s[1]);
    }

    // A-frags: x rows m0 + w*16 + n15, packed fp32->bf16
    int mrow = m0 + w * 16 + n15;
    bf8 afr[8];
#pragma unroll
    for (int kk = 0; kk < 8; kk++) {
        const float4* ap = (const float4*)(x + mrow * 256 + kk * 32 + quad * 8);
        afr[kk] = pack8(ap[0], ap[1]);
    }
    __syncthreads();

    f4 z = {0.f, 0.f, 0.f, 0.f};
    f4 c[4] = {z, z, z, z};
#pragma unroll
    for (int nt = 0; nt < 4; nt++) {
        const short* wr = &w_l[(nt * 16 + n15) * 264 + quad * 8];
#pragma unroll
        for (int kk = 0; kk < 8; kk++) {
            bf8 bfrag = *(const bf8*)(wr + kk * 32);
            c[nt] = __builtin_amdgcn_mfma_f32_16x16x32_bf16(afr[kk], bfrag, c[nt], 0, 0, 0);
        }
    }

    int mbase = m0 + w * 16 + quad * 4;
#pragma unroll
    for (int nt = 0; nt < 4; nt++) {
        int col = n0 + nt * 16 + n15;
        float bv = bias[col];
#pragma unroll
        for (int reg = 0; reg < 4; reg++)
            outp[(mbase + reg) * 256 + col] = bfr(c[nt][reg] + bv);
    }
}

// K2: fused qk + qr + softmax. Block = (b, 8-row i-tile): grid 256 x 512 thr.
// A-rows duplicated (row = n15&7): 16x16 MFMA tile carries 8 real rows; dup
// lanes hit identical cache lines. Single-barrier online softmax: each wave
// stores (m_w, sum_w exp(x-m_w)); recombine M,S per-thread after one barrier.
__global__ __launch_bounds__(512) void attn_kernel(const int* __restrict__ relations,
                                                   const short* __restrict__ ws,
                                                   float* __restrict__ out) {
    __shared__ float qr_l[16][112];
    __shared__ float2 red[16][8];   // {wave max, wave expsum}

    int blk = blockIdx.x;
    int b = blk >> 6;
    int i0 = (blk & 63) * 8;
    int gi0 = b * 512 + i0;
    int w = threadIdx.x >> 6;
    int lane = threadIdx.x & 63;
    int n15 = lane & 15, quad = lane >> 4;
    int j0 = w * 64;

    // prefetch relations: C row m=quad*4+reg -> real row (quad&1)*4+reg
    const int* rb = relations + (gi0 + (quad & 1) * 4) * 512 + j0 + n15;
    int rv[4][4];
#pragma unroll
    for (int reg = 0; reg < 4; reg++)
#pragma unroll
        for (int nt = 0; nt < 4; nt++)
            rv[nt][reg] = rb[reg * 512 + nt * 16];

    const short* qbf = ws + QBF;
    const short* kbf = ws + KBF;
    const short* rebf = ws + REBF;

    // A-frags: q row gi0 + (n15&7)  (rows 8..15 duplicate 0..7)
    int arow = gi0 + (n15 & 7);
    bf8 afr[8];
#pragma unroll
    for (int kk = 0; kk < 8; kk++)
        afr[kk] = *(const bf8*)(qbf + arow * 256 + kk * 32 + quad * 8);

    f4 z = {0.f, 0.f, 0.f, 0.f};
    f4 c[4] = {z, z, z, z};
#pragma unroll
    for (int nt = 0; nt < 4; nt++) {
        int krow = b * 512 + j0 + nt * 16 + n15;
        const short* kr = kbf + krow * 256 + quad * 8;
#pragma unroll
        for (int kk = 0; kk < 8; kk++) {
            bf8 bfrag = *(const bf8*)(kr + kk * 32);
            c[nt] = __builtin_amdgcn_mfma_f32_16x16x32_bf16(afr[kk], bfrag, c[nt], 0, 0, 0);
        }
    }

    if (w < 7) {  // qr tile: rel rows w*16..w*16+15 (rebf zero-padded to 112)
        f4 cq = z;
        const short* rr = rebf + (w * 16 + n15) * 256 + quad * 8;
#pragma unroll
        for (int kk = 0; kk < 8; kk++) {
            bf8 bfrag = *(const bf8*)(rr + kk * 32);
            cq = __builtin_amdgcn_mfma_f32_16x16x32_bf16(afr[kk], bfrag, cq, 0, 0, 0);
        }
#pragma unroll
        for (int reg = 0; reg < 4; reg++)
            qr_l[quad * 4 + reg][w * 16 + n15] = cq[reg];  // dup rows get dup values
    }
    __syncthreads();

    const float scale = 0.0625f;  // 1/sqrt(256)
    float lg[4][4];
#pragma unroll
    for (int nt = 0; nt < 4; nt++)
#pragma unroll
        for (int reg = 0; reg < 4; reg++)
            lg[nt][reg] = (c[nt][reg] + qr_l[quad * 4 + reg][rv[nt][reg]]) * scale;

    // wave-local (m, expsum) per row; shfl over the 16 n15 lanes only (d<=8)
    float pm[4], psum[4];
#pragma unroll
    for (int reg = 0; reg < 4; reg++) {
        float m = fmaxf(fmaxf(lg[0][reg], lg[1][reg]), fmaxf(lg[2][reg], lg[3][reg]));
#pragma unroll
        for (int d = 1; d <= 8; d <<= 1) m = fmaxf(m, __shfl_xor(m, d, 64));
        pm[reg] = m;
        float s = 0.f;
#pragma unroll
        for (int nt = 0; nt < 4; nt++) {
            float e = __expf(lg[nt][reg] - m);
            lg[nt][reg] = e;
            s += e;
        }
#pragma unroll
        for (int d = 1; d <= 8; d <<= 1) s += __shfl_xor(s, d, 64);
        psum[reg] = s;
    }
    if (n15 == 0)
#pragma unroll
        for (int reg = 0; reg < 4; reg++) {
            red[quad * 4 + reg][w].x = pm[reg];
            red[quad * 4 + reg][w].y = psum[reg];
        }
    __syncthreads();

    // recombine: M = max_w m_w ; S = sum_w s_w * exp(m_w - M); f = exp(pm-M)/S
    float f[4];
#pragma unroll
    for (int reg = 0; reg < 4; reg++) {
        int row = quad * 4 + reg;
        float2 p0 = red[row][0], p1 = red[row][1], p2 = red[row][2], p3 = red[row][3];
        float2 p4 = red[row][4], p5 = red[row][5], p6 = red[row][6], p7 = red[row][7];
        float M = fmaxf(fmaxf(fmaxf(p0.x, p1.x), fmaxf(p2.x, p3.x)),
                        fmaxf(fmaxf(p4.x, p5.x), fmaxf(p6.x, p7.x)));
        float S = p0.y * __expf(p0.x - M) + p1.y * __expf(p1.x - M) +
                  p2.y * __expf(p2.x - M) + p3.y * __expf(p3.x - M) +
                  p4.y * __expf(p4.x - M) + p5.y * __expf(p5.x - M) +
                  p6.y * __expf(p6.x - M) + p7.y * __expf(p7.x - M);
        f[reg] = __expf(pm[reg] - M) / S;
    }

    if (quad < 2) {  // rows 0..7 real; quads 2,3 are duplicates
        float* ob = out + (gi0 + quad * 4) * 512 + j0 + n15;
#pragma unroll
        for (int reg = 0; reg < 4; reg++)
#pragma unroll
            for (int nt = 0; nt < 4; nt++)
                ob[reg * 512 + nt * 16] = lg[nt][reg] * f[reg];
    }
}

extern "C" void kernel_launch(void* const* d_in, const int* in_sizes, int n_in,
                              void* d_out, int out_size, void* d_ws, size_t ws_size,
                              hipStream_t stream) {
    const float* queries = (const float*)d_in[0];
    const float* keys = (const float*)d_in[1];
    const int* relations = (const int*)d_in[2];
    const float* Wq = (const float*)d_in[3];
    const float* bq = (const float*)d_in[4];
    const float* Wk = (const float*)d_in[5];
    const float* bk = (const float*)d_in[6];
    const float* rel_emb = (const float*)d_in[7];
    short* wss = (short*)d_ws;
    float* out = (float*)d_out;

    hipLaunchKernelGGL(proj_kernel, dim3(263), dim3(256), 0, stream,
                       queries, keys, bq, bk, Wq, Wk, rel_emb, wss);
    hipLaunchKernelGGL(attn_kernel, dim3(256), dim3(512), 0, stream, relations, wss, out);
}

// Round 11
// 90.832 us; speedup vs baseline: 1.0570x; 1.0394x over previous
//
#include <hip/hip_runtime.h>

typedef __attribute__((ext_vector_type(8))) short bf8;
typedef __attribute__((ext_vector_type(4))) float f4;

// ws layout (short-element offsets)
#define QBF  0         // q  bf16 [2048][256]
#define KBF  524288    // k  bf16 [2048][256]
#define REBF 1048576   // rel_emb bf16 [112][256], rows 99..111 zero

static __device__ __forceinline__ short bfr(float x) {
    union { float f; unsigned u; } v; v.f = x;
    return (short)((v.u + 0x7FFF + ((v.u >> 16) & 1)) >> 16);  // RNE
}
static __device__ __forceinline__ bf8 pack8(float4 a, float4 b) {
    bf8 r;
    r[0] = bfr(a.x); r[1] = bfr(a.y); r[2] = bfr(a.z); r[3] = bfr(a.w);
    r[4] = bfr(b.x); r[5] = bfr(b.y); r[6] = bfr(b.z); r[7] = bfr(b.w);
    return r;
}

// K1: blocks 0..255: proj GEMM tiles (M=64 x N=64, 4 waves); blocks 256..262:
// rel_emb fp32->bf16 cast. out[row][col] = sum_h x[row][h]*W[col][h] + bias[col].
__global__ __launch_bounds__(256) void proj_kernel(const float* __restrict__ queries,
                                                   const float* __restrict__ keys,
                                                   const float* __restrict__ bq,
                                                   const float* __restrict__ bk,
                                                   const float* __restrict__ Wq,
                                                   const float* __restrict__ Wk,
                                                   const float* __restrict__ rel_emb,
                                                   short* __restrict__ ws) {
    __shared__ short w_l[64 * 264];  // bf16 W tile, row stride 264 shorts (16B-aligned)
    int blk = blockIdx.x;
    int tid = threadIdx.x;

    if (blk >= 256) {
        // rel_emb cast: 7 blocks x 256 thr x 16 shorts = 28672 = 112*256
        int idx = ((blk - 256) * 256 + tid) * 16;
        float4 a = make_float4(0.f, 0.f, 0.f, 0.f), b = a, c = a, d = a;
        if ((idx >> 8) < 99) {
            const float4* s = (const float4*)(rel_emb + idx);
            a = s[0]; b = s[1]; c = s[2]; d = s[3];
        }
        *(bf8*)(ws + REBF + idx) = pack8(a, b);
        *(bf8*)(ws + REBF + idx + 8) = pack8(c, d);
        return;
    }

    int mat = blk >> 7;          // 0 = q, 1 = k
    int t = blk & 127;           // 32 m-tiles x 4 n-tiles
    int m0 = (t >> 2) * 64;
    int n0 = (t & 3) * 64;
    const float* x = mat ? keys : queries;
    const float* W = mat ? Wk : Wq;
    const float* bias = mat ? bk : bq;
    short* outp = ws + (mat ? KBF : QBF);

    int w = tid >> 6;
    int lane = tid & 63;
    int n15 = lane & 15, quad = lane >> 4;

    // stage W[n0..n0+64)[0..256) fp32 -> bf16 LDS (coalesced 32B/lane reads)
#pragma unroll
    for (int cc = 0; cc < 8; cc++) {
        int chunk = cc * 256 + tid;          // 2048 chunks of 8 floats
        int row = chunk >> 5, col8 = chunk & 31;
        const float4* s = (const float4*)(W + (n0 + row) * 256 + col8 * 8);
        *(bf8*)&w_l[row * 264 + col8 * 8] = pack8(s[0], s[1]);
    }

    // A-frags: x rows m0 + w*16 + n15, packed fp32->bf16
    int mrow = m0 + w * 16 + n15;
    bf8 afr[8];
#pragma unroll
    for (int kk = 0; kk < 8; kk++) {
        const float4* ap = (const float4*)(x + mrow * 256 + kk * 32 + quad * 8);
        afr[kk] = pack8(ap[0], ap[1]);
    }
    __syncthreads();

    f4 z = {0.f, 0.f, 0.f, 0.f};
    f4 c[4] = {z, z, z, z};
#pragma unroll
    for (int nt = 0; nt < 4; nt++) {
        const short* wr = &w_l[(nt * 16 + n15) * 264 + quad * 8];
#pragma unroll
        for (int kk = 0; kk < 8; kk++) {
            bf8 bfrag = *(const bf8*)(wr + kk * 32);
            c[nt] = __builtin_amdgcn_mfma_f32_16x16x32_bf16(afr[kk], bfrag, c[nt], 0, 0, 0);
        }
    }

    int mbase = m0 + w * 16 + quad * 4;
#pragma unroll
    for (int nt = 0; nt < 4; nt++) {
        int col = n0 + nt * 16 + n15;
        float bv = bias[col];
#pragma unroll
        for (int reg = 0; reg < 4; reg++)
            outp[(mbase + reg) * 256 + col] = bfr(c[nt][reg] + bv);
    }
}

// K2: fused qk + qr + softmax. Block = (b, 8-row i-tile): grid 256 x 512 thr
// (full-device spread). A-rows duplicated (row = n15&7) so the 16x16 MFMA tile
// carries 8 real rows; dup lanes hit identical cache lines (L1/L2-absorbed).
// 3-barrier softmax (measured faster than online recombine: R8 91.1 vs R10 94.4
// — 32 extra quarter-rate __expf/thread cost more than one barrier).
__global__ __launch_bounds__(512) void attn_kernel(const int* __restrict__ relations,
                                                   const short* __restrict__ ws,
                                                   float* __restrict__ out) {
    __shared__ float qr_l[16][112];
    __shared__ float red_m[16][8];
    __shared__ float red_s[16][8];

    int blk = blockIdx.x;
    int b = blk >> 6;
    int i0 = (blk & 63) * 8;
    int gi0 = b * 512 + i0;
    int w = threadIdx.x >> 6;
    int lane = threadIdx.x & 63;
    int n15 = lane & 15, quad = lane >> 4;
    int j0 = w * 64;

    // prefetch relations: C row m=quad*4+reg -> real row (quad&1)*4+reg
    const int* rb = relations + (gi0 + (quad & 1) * 4) * 512 + j0 + n15;
    int rv[4][4];
#pragma unroll
    for (int reg = 0; reg < 4; reg++)
#pragma unroll
        for (int nt = 0; nt < 4; nt++)
            rv[nt][reg] = rb[reg * 512 + nt * 16];

    const short* qbf = ws + QBF;
    const short* kbf = ws + KBF;
    const short* rebf = ws + REBF;

    // A-frags: q row gi0 + (n15&7)  (rows 8..15 duplicate 0..7)
    int arow = gi0 + (n15 & 7);
    bf8 afr[8];
#pragma unroll
    for (int kk = 0; kk < 8; kk++)
        afr[kk] = *(const bf8*)(qbf + arow * 256 + kk * 32 + quad * 8);

    f4 z = {0.f, 0.f, 0.f, 0.f};
    f4 c[4] = {z, z, z, z};
#pragma unroll
    for (int nt = 0; nt < 4; nt++) {
        int krow = b * 512 + j0 + nt * 16 + n15;
        const short* kr = kbf + krow * 256 + quad * 8;
#pragma unroll
        for (int kk = 0; kk < 8; kk++) {
            bf8 bfrag = *(const bf8*)(kr + kk * 32);
            c[nt] = __builtin_amdgcn_mfma_f32_16x16x32_bf16(afr[kk], bfrag, c[nt], 0, 0, 0);
        }
    }

    if (w < 7) {  // qr tile: rel rows w*16..w*16+15 (rebf zero-padded to 112)
        f4 cq = z;
        const short* rr = rebf + (w * 16 + n15) * 256 + quad * 8;
#pragma unroll
        for (int kk = 0; kk < 8; kk++) {
            bf8 bfrag = *(const bf8*)(rr + kk * 32);
            cq = __builtin_amdgcn_mfma_f32_16x16x32_bf16(afr[kk], bfrag, cq, 0, 0, 0);
        }
#pragma unroll
        for (int reg = 0; reg < 4; reg++)
            qr_l[quad * 4 + reg][w * 16 + n15] = cq[reg];  // dup rows get dup values
    }
    __syncthreads();

    const float scale = 0.0625f;  // 1/sqrt(256)
    float lg[4][4];
#pragma unroll
    for (int nt = 0; nt < 4; nt++)
#pragma unroll
        for (int reg = 0; reg < 4; reg++)
            lg[nt][reg] = (c[nt][reg] + qr_l[quad * 4 + reg][rv[nt][reg]]) * scale;

    float pm[4];
#pragma unroll
    for (int reg = 0; reg < 4; reg++) {
        float m = fmaxf(fmaxf(lg[0][reg], lg[1][reg]), fmaxf(lg[2][reg], lg[3][reg]));
#pragma unroll
        for (int d = 1; d <= 8; d <<= 1) m = fmaxf(m, __shfl_xor(m, d, 64));
        pm[reg] = m;
    }
    if (n15 == 0)
#pragma unroll
        for (int reg = 0; reg < 4; reg++) red_m[quad * 4 + reg][w] = pm[reg];
    __syncthreads();
    float M[4];
#pragma unroll
    for (int reg = 0; reg < 4; reg++) {
        f4 a0 = *(const f4*)&red_m[quad * 4 + reg][0];
        f4 a1 = *(const f4*)&red_m[quad * 4 + reg][4];
        M[reg] = fmaxf(fmaxf(fmaxf(a0[0], a0[1]), fmaxf(a0[2], a0[3])),
                       fmaxf(fmaxf(a1[0], a1[1]), fmaxf(a1[2], a1[3])));
    }

    float ps[4];
#pragma unroll
    for (int reg = 0; reg < 4; reg++) {
        float s = 0.f;
#pragma unroll
        for (int nt = 0; nt < 4; nt++) {
            float e = __expf(lg[nt][reg] - M[reg]);
            lg[nt][reg] = e;
            s += e;
        }
#pragma unroll
        for (int d = 1; d <= 8; d <<= 1) s += __shfl_xor(s, d, 64);
        ps[reg] = s;
    }
    if (n15 == 0)
#pragma unroll
        for (int reg = 0; reg < 4; reg++) red_s[quad * 4 + reg][w] = ps[reg];
    __syncthreads();
    float inv[4];
#pragma unroll
    for (int reg = 0; reg < 4; reg++) {
        f4 a0 = *(const f4*)&red_s[quad * 4 + reg][0];
        f4 a1 = *(const f4*)&red_s[quad * 4 + reg][4];
        inv[reg] = 1.f / (a0[0] + a0[1] + a0[2] + a0[3] + a1[0] + a1[1] + a1[2] + a1[3]);
    }

    if (quad < 2) {  // rows 0..7 real; quads 2,3 are duplicates
        float* ob = out + (gi0 + quad * 4) * 512 + j0 + n15;
#pragma unroll
        for (int reg = 0; reg < 4; reg++)
#pragma unroll
            for (int nt = 0; nt < 4; nt++)
                ob[reg * 512 + nt * 16] = lg[nt][reg] * inv[reg];
    }
}

extern "C" void kernel_launch(void* const* d_in, const int* in_sizes, int n_in,
                              void* d_out, int out_size, void* d_ws, size_t ws_size,
                              hipStream_t stream) {
    const float* queries = (const float*)d_in[0];
    const float* keys = (const float*)d_in[1];
    const int* relations = (const int*)d_in[2];
    const float* Wq = (const float*)d_in[3];
    const float* bq = (const float*)d_in[4];
    const float* Wk = (const float*)d_in[5];
    const float* bk = (const float*)d_in[6];
    const float* rel_emb = (const float*)d_in[7];
    short* wss = (short*)d_ws;
    float* out = (float*)d_out;

    hipLaunchKernelGGL(proj_kernel, dim3(263), dim3(256), 0, stream,
                       queries, keys, bq, bk, Wq, Wk, rel_emb, wss);
    hipLaunchKernelGGL(attn_kernel, dim3(256), dim3(512), 0, stream, relations, wss, out);
}